// Round 1
// 718.209 us; speedup vs baseline: 1.0188x; 1.0188x over previous
//
#include <hip/hip_runtime.h>

// AI4DEM coupling_backward: 3x3 linear-spline P2G gather, 4096x4096, fp32.
// Algebraic facts (verified earlier, absmax 3.9e-3 pass):
//  - 0.5*(1 - S*xi)*in_range == max(0, 1 - |sgn|)  (hat), exact.
//  - mask is NOT rolled -> mask[y,x]*VP factors out of all 9 taps.
//  - x_grid/y_grid are arange meshgrids -> recomputed from indices.
//  - torus wrap taps get weight 0 automatically (|sgn| >> 1), so source rows
//    are wrapped for ADDRESSING only; hat args use unwrapped coordinates.
//
// R3: vertical rolling window. Previous structure loaded every source row 3x
// (54 window-load insts per 4 output cells) and was latency/TA-bound:
// HBM 2.45 TB/s, VALU 20%, both idle. Now each block owns a 16-row strip,
// iterates source rows ONCE (18 load insts per source row), contributing each
// source row into 3 pending output-row accumulators (ring of 3, statically
// rotated to keep everything in registers). hat_x reused across the 3 output
// rows. Mask row prefetched at step top so retire doesn't stall.

typedef float v4f __attribute__((ext_vector_type(4)));

static constexpr int NXd = 4096;
static constexpr int NYd = 4096;
static constexpr int H   = 16;          // output rows per block strip; H+2 = 18 steps (div by 3)

__device__ __forceinline__ float hat(float s) {
    return fmaxf(1.0f - fabsf(s), 0.0f);
}

// 6-wide window [x0-1, x0+4] as element offsets from base (32-bit voffsets).
__device__ __forceinline__ void load_window6(const float* __restrict__ base,
                                             int voff, int voffl, int voffr,
                                             float w[6]) {
    v4f v = *reinterpret_cast<const v4f*>(base + voff);
    w[0] = base[voffl];
    w[1] = v[0]; w[2] = v[1]; w[3] = v[2]; w[4] = v[3];
    w[5] = base[voffr];
}

struct Acc { float a[4], u[4], v[4], x[4], y[4]; };

__device__ __forceinline__ void zero_acc(Acc& A) {
    #pragma unroll
    for (int k = 0; k < 4; ++k) { A.a[k]=0.f; A.u[k]=0.f; A.v[k]=0.f; A.x[k]=0.f; A.y[k]=0.f; }
}

// Fold one source row's windows into one output-row accumulator.
// nx[k*3+c] = hat_x for output col k, tap c (shared across the 3 output rows).
// ny recomputed per output row (depends on yof).
__device__ __forceinline__ void accum(Acc& A, const float nx[12], const float wyp[6],
                                      float yof,
                                      const float wvx[6], const float wvy[6],
                                      const float wfx[6], const float wfy[6]) {
    float ny[6];
    #pragma unroll
    for (int i = 0; i < 6; ++i) ny[i] = hat(wyp[i] - yof);
    #pragma unroll
    for (int k = 0; k < 4; ++k) {
        const float w0 = nx[k*3+0] * ny[k+0];
        const float w1 = nx[k*3+1] * ny[k+1];
        const float w2 = nx[k*3+2] * ny[k+2];
        A.a[k] += (w0 + w1) + w2;
        A.u[k] = fmaf(w2, wvx[k+2], fmaf(w1, wvx[k+1], fmaf(w0, wvx[k+0], A.u[k])));
        A.v[k] = fmaf(w2, wvy[k+2], fmaf(w1, wvy[k+1], fmaf(w0, wvy[k+0], A.v[k])));
        A.x[k] = fmaf(w2, wfx[k+2], fmaf(w1, wfx[k+1], fmaf(w0, wfx[k+0], A.x[k])));
        A.y[k] = fmaf(w2, wfy[k+2], fmaf(w1, wfy[k+1], fmaf(w0, wfy[k+0], A.y[k])));
    }
}

__device__ __forceinline__ void retire(const Acc& A, v4f mv, int o, int x0,
                                       float* __restrict__ out) {
    const float VPf = (float)(3.1415 / 6.0);
    const size_t ob    = (size_t)o * NXd + x0;
    const size_t plane = (size_t)NXd * NYd;
    float m[4] = { mv[0]*VPf, mv[1]*VPf, mv[2]*VPf, mv[3]*VPf };
    v4f t;
    t[0]=A.a[0]*m[0]; t[1]=A.a[1]*m[1]; t[2]=A.a[2]*m[2]; t[3]=A.a[3]*m[3];
    __builtin_nontemporal_store(t, reinterpret_cast<v4f*>(out + ob));
    t[0]=A.u[0]*m[0]; t[1]=A.u[1]*m[1]; t[2]=A.u[2]*m[2]; t[3]=A.u[3]*m[3];
    __builtin_nontemporal_store(t, reinterpret_cast<v4f*>(out + plane + ob));
    t[0]=A.v[0]*m[0]; t[1]=A.v[1]*m[1]; t[2]=A.v[2]*m[2]; t[3]=A.v[3]*m[3];
    __builtin_nontemporal_store(t, reinterpret_cast<v4f*>(out + 2*plane + ob));
    t[0]=A.x[0]*m[0]; t[1]=A.x[1]*m[1]; t[2]=A.x[2]*m[2]; t[3]=A.x[3]*m[3];
    __builtin_nontemporal_store(t, reinterpret_cast<v4f*>(out + 3*plane + ob));
    t[0]=A.y[0]*m[0]; t[1]=A.y[1]*m[1]; t[2]=A.y[2]*m[2]; t[3]=A.y[3]*m[3];
    __builtin_nontemporal_store(t, reinterpret_cast<v4f*>(out + 4*plane + ob));
}

// One source-row step. Contributions to out rows (yu-1, yu, yu+1) held in
// (AM1, A0, AP1); AM1 is complete after this step -> retire if live, re-zero.
#define STEP(T, AM1, A0, AP1)                                                  \
  {                                                                            \
    const int t  = (T);                                                        \
    const int yu = ys - 1 + t;                     /* unwrapped source row */  \
    const int yy = (yu < 0) ? (NYd - 1) : ((yu >= NYd) ? 0 : yu);              \
    const int rb = yy * NXd;                                                   \
    const int voff  = rb + x0;                                                 \
    const int voffl = rb + xl;                                                 \
    const int voffr = rb + xr;                                                 \
    const bool live = (t >= 2);                    /* retiring row in strip */ \
    v4f mv{};                                                                  \
    if (live) mv = *reinterpret_cast<const v4f*>(mask + (size_t)(yu-1)*NXd + x0); \
    float wxp[6], wyp[6], wvx[6], wvy[6], wfx[6], wfy[6];                      \
    load_window6(xp,  voff, voffl, voffr, wxp);                                \
    load_window6(yp,  voff, voffl, voffr, wyp);                                \
    load_window6(vx,  voff, voffl, voffr, wvx);                                \
    load_window6(vy,  voff, voffl, voffr, wvy);                                \
    load_window6(fxg, voff, voffl, voffr, wfx);                                \
    load_window6(fyg, voff, voffl, voffr, wfy);                                \
    float nx[12];                                                              \
    _Pragma("unroll")                                                          \
    for (int k = 0; k < 4; ++k) {                                              \
      _Pragma("unroll")                                                        \
      for (int c = 0; c < 3; ++c)                                              \
        nx[k*3+c] = hat(wxp[k+c] - (xf0 + (float)k));                          \
    }                                                                          \
    const float yuf = (float)yu;                                               \
    accum(AM1, nx, wyp, yuf - 1.0f, wvx, wvy, wfx, wfy);                       \
    accum(A0,  nx, wyp, yuf,        wvx, wvy, wfx, wfy);                       \
    accum(AP1, nx, wyp, yuf + 1.0f, wvx, wvy, wfx, wfy);                       \
    if (live) retire(AM1, mv, yu - 1, x0, out);                                \
    zero_acc(AM1);                                                             \
  }

__global__ __launch_bounds__(256) void ai4dem_kernel(
    const float* __restrict__ xp, const float* __restrict__ yp,
    const float* __restrict__ vx, const float* __restrict__ vy,
    const float* __restrict__ fxg, const float* __restrict__ fyg,
    const float* __restrict__ mask, float* __restrict__ out)
{
    const int tx = threadIdx.x;                    // 0..255
    const int x0 = (blockIdx.x * 256 + tx) * 4;    // 4 columns per thread
    const int ys = blockIdx.y * H;                 // strip start row

    const int xl = (x0 == 0)       ? (NXd - 1) : (x0 - 1);
    const int xr = (x0 + 4 >= NXd) ? 0         : (x0 + 4);
    const float xf0 = (float)x0;

    Acc A, B, C;
    zero_acc(A); zero_acc(B); zero_acc(C);

    // 18 source-row steps; ring rotation has period 3, so any unroll of this
    // loop preserves the static slot naming. Unroll 2 keeps the body ~6 steps
    // (I$-safe) while letting the scheduler pipeline loads across steps.
    #pragma unroll 2
    for (int it = 0; it < (H + 2) / 3; ++it) {
        const int tb = it * 3;
        STEP(tb + 0, A, B, C);
        STEP(tb + 1, B, C, A);
        STEP(tb + 2, C, A, B);
    }
}

extern "C" void kernel_launch(void* const* d_in, const int* in_sizes, int n_in,
                              void* d_out, int out_size, void* d_ws, size_t ws_size,
                              hipStream_t stream) {
    // setup_inputs order: xp, yp, x_grid, y_grid, vx, vy, Fx, Fy, mask
    const float* xp   = (const float*)d_in[0];
    const float* yp   = (const float*)d_in[1];
    // d_in[2], d_in[3] (x_grid, y_grid) recomputed from indices.
    const float* vx   = (const float*)d_in[4];
    const float* vy   = (const float*)d_in[5];
    const float* fxg  = (const float*)d_in[6];
    const float* fyg  = (const float*)d_in[7];
    const float* mask = (const float*)d_in[8];
    float* out = (float*)d_out;

    dim3 block(256, 1, 1);
    dim3 grid(NXd / 1024, NYd / H, 1);   // (4, 256) = 1024 blocks, 4096 waves
    hipLaunchKernelGGL(ai4dem_kernel, grid, block, 0, stream,
                       xp, yp, vx, vy, fxg, fyg, mask, out);
}

// Round 2
// 691.797 us; speedup vs baseline: 1.0577x; 1.0382x over previous
//
#include <hip/hip_runtime.h>

// AI4DEM coupling_backward: 3x3 linear-spline P2G gather, 4096x4096, fp32.
// Algebraic facts (verified earlier, absmax 3.9e-3 pass):
//  - 0.5*(1 - S*xi)*in_range == max(0, 1 - |sgn|)  (hat), exact.
//  - mask is NOT rolled -> mask[y,x]*VP factors out of all 9 taps.
//  - x_grid/y_grid are arange meshgrids -> recomputed from indices.
//  - torus wrap taps get weight 0 automatically (|sgn| >> 1), so source rows
//    are wrapped for ADDRESSING only; hat args use unwrapped coordinates.
//
// R3 post-mortem: rolling window cut loads 3x but also cut waves 16x
// (4096 waves, occ 21%) -> still latency-bound at 2.5 TB/s, VALU 13%.
// Both pipes idle across two different kernels at the same BW = MLP-starved
// (Little's law), not throughput-bound.
// R4: H=16 -> H=8. 2048 blocks, 8192 waves = 32/CU wanted (VGPR-capped ~20/CU).
// Only occupancy changes; load structure identical to isolate the variable.

typedef float v4f __attribute__((ext_vector_type(4)));

static constexpr int NXd = 4096;
static constexpr int NYd = 4096;
static constexpr int H   = 8;           // output rows per block strip; H+2 = 10 steps

__device__ __forceinline__ float hat(float s) {
    return fmaxf(1.0f - fabsf(s), 0.0f);
}

// 6-wide window [x0-1, x0+4] as element offsets from base (32-bit voffsets).
__device__ __forceinline__ void load_window6(const float* __restrict__ base,
                                             int voff, int voffl, int voffr,
                                             float w[6]) {
    v4f v = *reinterpret_cast<const v4f*>(base + voff);
    w[0] = base[voffl];
    w[1] = v[0]; w[2] = v[1]; w[3] = v[2]; w[4] = v[3];
    w[5] = base[voffr];
}

struct Acc { float a[4], u[4], v[4], x[4], y[4]; };

__device__ __forceinline__ void zero_acc(Acc& A) {
    #pragma unroll
    for (int k = 0; k < 4; ++k) { A.a[k]=0.f; A.u[k]=0.f; A.v[k]=0.f; A.x[k]=0.f; A.y[k]=0.f; }
}

// Fold one source row's windows into one output-row accumulator.
// nx[k*3+c] = hat_x for output col k, tap c (shared across the 3 output rows).
// ny recomputed per output row (depends on yof).
__device__ __forceinline__ void accum(Acc& A, const float nx[12], const float wyp[6],
                                      float yof,
                                      const float wvx[6], const float wvy[6],
                                      const float wfx[6], const float wfy[6]) {
    float ny[6];
    #pragma unroll
    for (int i = 0; i < 6; ++i) ny[i] = hat(wyp[i] - yof);
    #pragma unroll
    for (int k = 0; k < 4; ++k) {
        const float w0 = nx[k*3+0] * ny[k+0];
        const float w1 = nx[k*3+1] * ny[k+1];
        const float w2 = nx[k*3+2] * ny[k+2];
        A.a[k] += (w0 + w1) + w2;
        A.u[k] = fmaf(w2, wvx[k+2], fmaf(w1, wvx[k+1], fmaf(w0, wvx[k+0], A.u[k])));
        A.v[k] = fmaf(w2, wvy[k+2], fmaf(w1, wvy[k+1], fmaf(w0, wvy[k+0], A.v[k])));
        A.x[k] = fmaf(w2, wfx[k+2], fmaf(w1, wfx[k+1], fmaf(w0, wfx[k+0], A.x[k])));
        A.y[k] = fmaf(w2, wfy[k+2], fmaf(w1, wfy[k+1], fmaf(w0, wfy[k+0], A.y[k])));
    }
}

__device__ __forceinline__ void retire(const Acc& A, v4f mv, int o, int x0,
                                       float* __restrict__ out) {
    const float VPf = (float)(3.1415 / 6.0);
    const size_t ob    = (size_t)o * NXd + x0;
    const size_t plane = (size_t)NXd * NYd;
    float m[4] = { mv[0]*VPf, mv[1]*VPf, mv[2]*VPf, mv[3]*VPf };
    v4f t;
    t[0]=A.a[0]*m[0]; t[1]=A.a[1]*m[1]; t[2]=A.a[2]*m[2]; t[3]=A.a[3]*m[3];
    __builtin_nontemporal_store(t, reinterpret_cast<v4f*>(out + ob));
    t[0]=A.u[0]*m[0]; t[1]=A.u[1]*m[1]; t[2]=A.u[2]*m[2]; t[3]=A.u[3]*m[3];
    __builtin_nontemporal_store(t, reinterpret_cast<v4f*>(out + plane + ob));
    t[0]=A.v[0]*m[0]; t[1]=A.v[1]*m[1]; t[2]=A.v[2]*m[2]; t[3]=A.v[3]*m[3];
    __builtin_nontemporal_store(t, reinterpret_cast<v4f*>(out + 2*plane + ob));
    t[0]=A.x[0]*m[0]; t[1]=A.x[1]*m[1]; t[2]=A.x[2]*m[2]; t[3]=A.x[3]*m[3];
    __builtin_nontemporal_store(t, reinterpret_cast<v4f*>(out + 3*plane + ob));
    t[0]=A.y[0]*m[0]; t[1]=A.y[1]*m[1]; t[2]=A.y[2]*m[2]; t[3]=A.y[3]*m[3];
    __builtin_nontemporal_store(t, reinterpret_cast<v4f*>(out + 4*plane + ob));
}

// One source-row step. Contributions to out rows (yu-1, yu, yu+1) held in
// (AM1, A0, AP1); AM1 is complete after this step -> retire if live, re-zero.
#define STEP(T, AM1, A0, AP1)                                                  \
  {                                                                            \
    const int t  = (T);                                                        \
    const int yu = ys - 1 + t;                     /* unwrapped source row */  \
    const int yy = (yu < 0) ? (NYd - 1) : ((yu >= NYd) ? 0 : yu);              \
    const int rb = yy * NXd;                                                   \
    const int voff  = rb + x0;                                                 \
    const int voffl = rb + xl;                                                 \
    const int voffr = rb + xr;                                                 \
    const bool live = (t >= 2);                    /* retiring row in strip */ \
    v4f mv{};                                                                  \
    if (live) mv = *reinterpret_cast<const v4f*>(mask + (size_t)(yu-1)*NXd + x0); \
    float wxp[6], wyp[6], wvx[6], wvy[6], wfx[6], wfy[6];                      \
    load_window6(xp,  voff, voffl, voffr, wxp);                                \
    load_window6(yp,  voff, voffl, voffr, wyp);                                \
    load_window6(vx,  voff, voffl, voffr, wvx);                                \
    load_window6(vy,  voff, voffl, voffr, wvy);                                \
    load_window6(fxg, voff, voffl, voffr, wfx);                                \
    load_window6(fyg, voff, voffl, voffr, wfy);                                \
    float nx[12];                                                              \
    _Pragma("unroll")                                                          \
    for (int k = 0; k < 4; ++k) {                                              \
      _Pragma("unroll")                                                        \
      for (int c = 0; c < 3; ++c)                                              \
        nx[k*3+c] = hat(wxp[k+c] - (xf0 + (float)k));                          \
    }                                                                          \
    const float yuf = (float)yu;                                               \
    accum(AM1, nx, wyp, yuf - 1.0f, wvx, wvy, wfx, wfy);                       \
    accum(A0,  nx, wyp, yuf,        wvx, wvy, wfx, wfy);                       \
    accum(AP1, nx, wyp, yuf + 1.0f, wvx, wvy, wfx, wfy);                       \
    if (live) retire(AM1, mv, yu - 1, x0, out);                                \
    zero_acc(AM1);                                                             \
  }

__global__ __launch_bounds__(256) void ai4dem_kernel(
    const float* __restrict__ xp, const float* __restrict__ yp,
    const float* __restrict__ vx, const float* __restrict__ vy,
    const float* __restrict__ fxg, const float* __restrict__ fyg,
    const float* __restrict__ mask, float* __restrict__ out)
{
    const int tx = threadIdx.x;                    // 0..255
    const int x0 = (blockIdx.x * 256 + tx) * 4;    // 4 columns per thread
    const int ys = blockIdx.y * H;                 // strip start row

    const int xl = (x0 == 0)       ? (NXd - 1) : (x0 - 1);
    const int xr = (x0 + 4 >= NXd) ? 0         : (x0 + 4);
    const float xf0 = (float)x0;

    Acc A, B, C;
    zero_acc(A); zero_acc(B); zero_acc(C);

    // 10 source-row steps (t=0..9); ring rotation period 3, so 3 rolled
    // iterations of 3 steps + one trailing step keep slot naming static.
    // Rolled loop (no unroll) keeps the body ~3 steps for I$.
    #pragma unroll 1
    for (int it = 0; it < 3; ++it) {
        const int tb = it * 3;
        STEP(tb + 0, A, B, C);
        STEP(tb + 1, B, C, A);
        STEP(tb + 2, C, A, B);
    }
    STEP(9, A, B, C);
}

extern "C" void kernel_launch(void* const* d_in, const int* in_sizes, int n_in,
                              void* d_out, int out_size, void* d_ws, size_t ws_size,
                              hipStream_t stream) {
    // setup_inputs order: xp, yp, x_grid, y_grid, vx, vy, Fx, Fy, mask
    const float* xp   = (const float*)d_in[0];
    const float* yp   = (const float*)d_in[1];
    // d_in[2], d_in[3] (x_grid, y_grid) recomputed from indices.
    const float* vx   = (const float*)d_in[4];
    const float* vy   = (const float*)d_in[5];
    const float* fxg  = (const float*)d_in[6];
    const float* fyg  = (const float*)d_in[7];
    const float* mask = (const float*)d_in[8];
    float* out = (float*)d_out;

    dim3 block(256, 1, 1);
    dim3 grid(NXd / 1024, NYd / H, 1);   // (4, 512) = 2048 blocks, 8192 waves
    hipLaunchKernelGGL(ai4dem_kernel, grid, block, 0, stream,
                       xp, yp, vx, vy, fxg, fyg, mask, out);
}